// Round 17
// baseline (122.287 us; speedup 1.0000x reference)
//
#include <hip/hip_runtime.h>
#include <math.h>

#define DDIM 4096
#define NSEG 100
#define HDIM 128
#define BROWS 4096
#define TOPK 10
#define KSLICES 8

typedef __attribute__((ext_vector_type(8))) short bf16x8;
typedef __attribute__((ext_vector_type(4))) float f32x4;
typedef __attribute__((ext_vector_type(2))) float f32x2;

// async global->LDS, 16 B per lane; dest = uniform base + lane*16 (HW rule).
__device__ __forceinline__ void gl16(const void* g, void* l) {
    __builtin_amdgcn_global_load_lds(
        (const __attribute__((address_space(1))) unsigned int*)g,
        (__attribute__((address_space(3))) unsigned int*)l,
        16, 0, 0);
}

// Branch-free gelu: A&S 7.1.26 erf (abs err <= 1.5e-7), v_exp_f32 + v_rcp_f32.
__device__ __forceinline__ float gelu_f(float x) {
    float u  = x * 0.70710678118654752440f;
    float au = fminf(fabsf(u), 3.9f);                 // erf(3.9) == 1 to fp32
    float t  = __builtin_amdgcn_rcpf(fmaf(0.3275911f, au, 1.0f));
    float p  = fmaf(fmaf(fmaf(fmaf(1.061405429f, t, -1.453152027f), t,
                              1.421413741f), t, -0.284496736f), t, 0.254829592f) * t;
    float e  = __expf(-au * au);
    float er = fmaf(-p, e, 1.0f);                     // erf(|u|)
    er = copysignf(er, u);
    return 0.5f * x * (1.0f + er);
}

// Packed-pair gelu: identical math per component (VOP3P v_pk_* IEEE == scalar).
__device__ __forceinline__ f32x2 gelu2(f32x2 x) {
    f32x2 u  = x * 0.70710678118654752440f;
    f32x2 au = __builtin_elementwise_min(__builtin_elementwise_abs(u), (f32x2)(3.9f));
    f32x2 den = __builtin_elementwise_fma((f32x2)(0.3275911f), au, (f32x2)(1.0f));
    f32x2 t;
    t.x = __builtin_amdgcn_rcpf(den.x);
    t.y = __builtin_amdgcn_rcpf(den.y);
    f32x2 p = __builtin_elementwise_fma(
                __builtin_elementwise_fma(
                  __builtin_elementwise_fma(
                    __builtin_elementwise_fma((f32x2)(1.061405429f), t, (f32x2)(-1.453152027f)),
                    t, (f32x2)(1.421413741f)),
                  t, (f32x2)(-0.284496736f)),
                t, (f32x2)(0.254829592f)) * t;
    f32x2 e;
    e.x = __expf(-au.x * au.x);
    e.y = __expf(-au.y * au.y);
    f32x2 er = __builtin_elementwise_fma(-p, e, (f32x2)(1.0f));
    er.x = copysignf(er.x, u.x);
    er.y = copysignf(er.y, u.y);
    return 0.5f * x * ((f32x2)(1.0f) + er);
}

// Split fp32 -> bf16 hi (truncate) + bf16 lo (exact residual, truncated).
__device__ __forceinline__ void split8(const float4& a, const float4& b,
                                       bf16x8& hi, bf16x8& lo) {
    float v[8] = {a.x, a.y, a.z, a.w, b.x, b.y, b.z, b.w};
    uint hw[4], lw[4];
    #pragma unroll
    for (int j = 0; j < 4; ++j) {
        uint u0 = __float_as_uint(v[2 * j]);
        uint u1 = __float_as_uint(v[2 * j + 1]);
        hw[j] = (u0 >> 16) | (u1 & 0xffff0000u);
        float r0 = v[2 * j]     - __uint_as_float(u0 & 0xffff0000u);
        float r1 = v[2 * j + 1] - __uint_as_float(u1 & 0xffff0000u);
        lw[j] = (__float_as_uint(r0) >> 16) | (__float_as_uint(r1) & 0xffff0000u);
    }
    uint4 h = make_uint4(hw[0], hw[1], hw[2], hw[3]);
    uint4 l = make_uint4(lw[0], lw[1], lw[2], lw[3]);
    hi = __builtin_bit_cast(bf16x8, h);
    lo = __builtin_bit_cast(bf16x8, l);
}

// ---------- K_front: seg_gemm (0..1599) || bt (1600..1727) || segI (1728..1855) ----------
// segI: seg -> per-(dblock,kstep) pre-swizzled bf16 hi/lo images for k_wgemm's B.
// chunk c2 = db*4 + ks, 16 KB each {hi 8K | lo 8K}, Z(col,u) = (col*64+u*16)^((col&7)<<4);
// element (col,u,j2): seg[k = ks*32 + u*8 + j2][d = db*128 + col], k>=100 -> 0.
__global__ void k_front(const float* __restrict__ seg,
                        const float* __restrict__ iw1,
                        const float* __restrict__ rw1,
                        float* __restrict__ segp,
                        unsigned char* __restrict__ btI,
                        unsigned char* __restrict__ segI) {
    __shared__ __align__(16) float shf[32 * 129];   // 16.5 KB, union for all parts
    int bid = blockIdx.x, tid = threadIdx.x;
    if (bid < 1600) {
        float (*segT)[5] = reinterpret_cast<float (*)[5]>(shf);
        int ng = bid % 25;
        int ks = (bid / 25) * 64;
        {
            int k = tid & 63, j = tid >> 6;
            segT[k][j] = seg[(size_t)(ng * 4 + j) * DDIM + ks + k];
        }
        __syncthreads();
        int col = tid;
        float a0 = 0.f, a1 = 0.f, a2 = 0.f, a3 = 0.f;
        const float* w = (col < HDIM) ? (iw1 + col)
                                      : (rw1 + (size_t)DDIM * HDIM + (col - HDIM));
        #pragma unroll 8
        for (int k = 0; k < 64; ++k) {
            float wv = w[(size_t)(ks + k) * HDIM];
            a0 = fmaf(segT[k][0], wv, a0);
            a1 = fmaf(segT[k][1], wv, a1);
            a2 = fmaf(segT[k][2], wv, a2);
            a3 = fmaf(segT[k][3], wv, a3);
        }
        float* outp = segp + (size_t)(bid / 25) * (NSEG * 256) + (size_t)(ng * 4) * 256 + col;
        outp[0] = a0; outp[256] = a1; outp[512] = a2; outp[768] = a3;
    } else if (bid < 1728) {
        float (*tile)[129] = reinterpret_cast<float (*)[129]>(shf);
        int c = bid - 1600;
        #pragma unroll
        for (int i = 0; i < 4; ++i) {
            int e = i * 1024 + tid * 4;
            int k = e >> 7, n = e & 127;
            *reinterpret_cast<float4*>(&tile[k][n]) =
                *reinterpret_cast<const float4*>(rw1 + (size_t)(c * 32 + k) * HDIM + n);
        }
        __syncthreads();
        unsigned char* img = btI + (size_t)c * 16384;
        #pragma unroll
        for (int uu = 0; uu < 2; ++uu) {
            int U = tid * 2 + uu;            // 0..511
            int col = U >> 2;
            int u = U & 3;
            int Z = (col * 64 + u * 16) ^ ((col & 7) << 4);
            uint hw[4], lw[4];
            #pragma unroll
            for (int j = 0; j < 4; ++j) {
                float x0 = tile[u * 8 + 2 * j][col];
                float x1 = tile[u * 8 + 2 * j + 1][col];
                uint u0 = __float_as_uint(x0), u1 = __float_as_uint(x1);
                hw[j] = (u0 >> 16) | (u1 & 0xffff0000u);
                float r0 = x0 - __uint_as_float(u0 & 0xffff0000u);
                float r1 = x1 - __uint_as_float(u1 & 0xffff0000u);
                lw[j] = (__float_as_uint(r0) >> 16) | (__float_as_uint(r1) & 0xffff0000u);
            }
            *reinterpret_cast<uint4*>(img + Z)        = make_uint4(hw[0], hw[1], hw[2], hw[3]);
            *reinterpret_cast<uint4*>(img + 8192 + Z) = make_uint4(lw[0], lw[1], lw[2], lw[3]);
        }
    } else {
        float (*tile)[129] = reinterpret_cast<float (*)[129]>(shf);
        int c2 = bid - 1728;                 // chunk index = db*4 + ks
        int db = c2 >> 2, ks = c2 & 3;
        #pragma unroll
        for (int i = 0; i < 4; ++i) {
            int e = i * 1024 + tid * 4;
            int k = e >> 7, n = e & 127;
            int gk = ks * 32 + k;
            float4 v = (gk < NSEG)
                ? *reinterpret_cast<const float4*>(seg + (size_t)gk * DDIM + db * 128 + n)
                : make_float4(0.f, 0.f, 0.f, 0.f);
            *reinterpret_cast<float4*>(&tile[k][n]) = v;
        }
        __syncthreads();
        unsigned char* img = segI + (size_t)c2 * 16384;
        #pragma unroll
        for (int uu = 0; uu < 2; ++uu) {
            int U = tid * 2 + uu;
            int col = U >> 2;
            int u = U & 3;
            int Z = (col * 64 + u * 16) ^ ((col & 7) << 4);
            uint hw[4], lw[4];
            #pragma unroll
            for (int j = 0; j < 4; ++j) {
                float x0 = tile[u * 8 + 2 * j][col];
                float x1 = tile[u * 8 + 2 * j + 1][col];
                uint u0 = __float_as_uint(x0), u1 = __float_as_uint(x1);
                hw[j] = (u0 >> 16) | (u1 & 0xffff0000u);
                float r0 = x0 - __uint_as_float(u0 & 0xffff0000u);
                float r1 = x1 - __uint_as_float(u1 & 0xffff0000u);
                lw[j] = (__float_as_uint(r0) >> 16) | (__float_as_uint(r1) & 0xffff0000u);
            }
            *reinterpret_cast<uint4*>(img + Z)        = make_uint4(hw[0], hw[1], hw[2], hw[3]);
            *reinterpret_cast<uint4*>(img + 8192 + Z) = make_uint4(lw[0], lw[1], lw[2], lw[3]);
        }
    }
}

// ---------- K_mid: qh_mfma (blocks 0..511) || seg_red (blocks 512..611) ----------
__global__ __launch_bounds__(256)
void k_mid(const float* __restrict__ query,
           const unsigned char* __restrict__ btI,
           float* __restrict__ qhp,
           const float* __restrict__ segp,
           const int* __restrict__ positions,
           const float* __restrict__ ib1,
           const float* __restrict__ iw2,
           const float* __restrict__ ib2,
           const float* __restrict__ rb1,
           float* __restrict__ shwT, float* __restrict__ impA,
           float* __restrict__ cA) {
    __shared__ __align__(16) char lds[49152];       // qh: Ab 16K | Bb 32K; seg_red: red 512B
    int bid = blockIdx.x, tid = threadIdx.x;
    if (bid < 512) {
        float  (*Ab)[2048] = reinterpret_cast<float (*)[2048]>(lds);
        ushort (*Bb)[8192] = reinterpret_cast<ushort (*)[8192]>(lds + 16384);
        int lane = tid & 63, w = tid >> 6;
        int cl = lane & 15, rg = lane >> 4;
        int wm = w >> 1, wn = w & 1;       // wave quadrant: 32 rows x 64 cols
        int m0 = (bid & 63) * 64;
        int ky = bid >> 6;
        int k0 = ky * 512;

        const float* aSrc0;
        const float* aSrc1;
        {
            int X0 = w * 2048 + lane * 16;
            int r0_ = X0 >> 7, kb0 = (X0 & 127) ^ ((r0_ & 7) << 4);
            aSrc0 = query + (size_t)(m0 + r0_) * DDIM + k0 + (kb0 >> 2);
            int X1 = X0 + 1024;
            int r1_ = X1 >> 7, kb1 = (X1 & 127) ^ ((r1_ & 7) << 4);
            aSrc1 = query + (size_t)(m0 + r1_) * DDIM + k0 + (kb1 >> 2);
        }
        const unsigned char* bSrc = btI + (size_t)(ky * 16) * 16384 + w * 4096 + lane * 16;

        f32x4 acc[2][4];
        #pragma unroll
        for (int mi = 0; mi < 2; ++mi)
            #pragma unroll
            for (int nf = 0; nf < 4; ++nf) acc[mi][nf] = (f32x4)0.f;

        {
            char* ad = (char*)&Ab[0][0] + w * 2048;
            char* bd = (char*)&Bb[0][0] + w * 4096;
            gl16(aSrc0, ad);
            gl16(aSrc1, ad + 1024);
            #pragma unroll
            for (int j = 0; j < 4; ++j) gl16(bSrc + j * 1024, bd + j * 1024);
        }
        __syncthreads();

        #pragma unroll 2
        for (int t = 0; t < 16; ++t) {
            int cur = t & 1;
            if (t < 15) {
                char* ad = (char*)&Ab[cur ^ 1][0] + w * 2048;
                char* bd = (char*)&Bb[cur ^ 1][0] + w * 4096;
                gl16(aSrc0 + (t + 1) * 32, ad);
                gl16(aSrc1 + (t + 1) * 32, ad + 1024);
                const unsigned char* bs = bSrc + (size_t)(t + 1) * 16384;
                #pragma unroll
                for (int j = 0; j < 4; ++j) gl16(bs + j * 1024, bd + j * 1024);
            }
            bf16x8 ah[2], al[2];
            #pragma unroll
            for (int mi = 0; mi < 2; ++mi) {
                int row = wm * 32 + mi * 16 + cl;
                int sw = (row & 7) << 4;
                int Sb = row * 128 + rg * 32;
                float4 f0 = *reinterpret_cast<const float4*>((const char*)&Ab[cur][0] + (Sb ^ sw));
                float4 f1 = *reinterpret_cast<const float4*>((const char*)&Ab[cur][0] + ((Sb + 16) ^ sw));
                split8(f0, f1, ah[mi], al[mi]);
            }
            #pragma unroll
            for (int nf = 0; nf < 4; ++nf) {
                int col = wn * 64 + nf * 16 + cl;
                int Z = (col * 64 + rg * 16) ^ ((col & 7) << 4);
                // buffer layout: {hi 0..8191 | lo 8192..16383} BYTES within Bb[cur]
                bf16x8 bh = *reinterpret_cast<const bf16x8*>((const char*)&Bb[cur][0] + Z);
                bf16x8 bl = *reinterpret_cast<const bf16x8*>((const char*)&Bb[cur][0] + 8192 + Z);
                #pragma unroll
                for (int mi = 0; mi < 2; ++mi) {
                    acc[mi][nf] = __builtin_amdgcn_mfma_f32_16x16x32_bf16(ah[mi], bh, acc[mi][nf], 0, 0, 0);
                    acc[mi][nf] = __builtin_amdgcn_mfma_f32_16x16x32_bf16(al[mi], bh, acc[mi][nf], 0, 0, 0);
                    acc[mi][nf] = __builtin_amdgcn_mfma_f32_16x16x32_bf16(ah[mi], bl, acc[mi][nf], 0, 0, 0);
                }
            }
            __syncthreads();
        }

        float* op = qhp + (size_t)ky * (BROWS * HDIM);
        #pragma unroll
        for (int mi = 0; mi < 2; ++mi) {
            int rowb = m0 + wm * 32 + mi * 16 + rg * 4;
            #pragma unroll
            for (int nf = 0; nf < 4; ++nf) {
                int col = wn * 64 + nf * 16 + cl;
                #pragma unroll
                for (int r = 0; r < 4; ++r)
                    op[(size_t)(rowb + r) * HDIM + col] = acc[mi][nf][r];
            }
        }
    } else {
        float* red = reinterpret_cast<float*>(lds);
        int n = bid - 512;
        float v = 0.f;
        #pragma unroll
        for (int s = 0; s < 64; ++s)
            v += segp[(size_t)s * (NSEG * 256) + (size_t)n * 256 + tid];
        if (tid < HDIM) {
            red[tid] = gelu_f(v + ib1[tid]) * iw2[tid];
        } else {
            shwT[(size_t)(tid - HDIM) * NSEG + n] = v + rb1[tid - HDIM];
        }
        __syncthreads();
        if (tid == 0) {
            float s = 0.f;
            for (int j = 0; j < HDIM; ++j) s += red[j];
            float imp = 1.f / (1.f + expf(-(s + ib2[0])));
            float pf = powf(0.95f, (float)NSEG - (float)positions[n] - 1.0f);
            impA[n] = imp;
            cA[n] = imp * (0.5f + 0.5f * pf);
        }
    }
}

// ---------- K4a: rel scores + top-10 -> dense bf16 W rows (hi/lo) ----------
// grid 1024, block 256 (4 waves): wave w owns row b0+w; lane l owns segments
// {2l, 2l+1}. Packed f32x2 gelu + 4 independent h-slice chains. After the
// butterfly, idxv/wv/wsum are uniform across ALL lanes -> each lane writes its
// 2 columns of the dense normalized-weight row (0 if not selected), split to
// bf16 hi/lo for the k_wgemm MFMA.
__global__ __launch_bounds__(256)
void k_rel(const float* __restrict__ qhp,
           const float* __restrict__ shwT,
           const float* __restrict__ rw2,
           const float* __restrict__ rb2,
           const float* __restrict__ impA,
           const float* __restrict__ cA,
           ushort* __restrict__ Wh,
           ushort* __restrict__ Wl) {
    __shared__ float qs[4][HDIM];
    __shared__ float scL[4][128], wiL[4][128];
    int tid = threadIdx.x;
    int b0 = blockIdx.x * 4;

    // stage qs: 4 rows x 128 h = 512 sums; thread stages idx = tid, tid+256
    #pragma unroll
    for (int i = 0; i < 2; ++i) {
        int idx = tid + i * 256;
        int r = idx >> 7, h = idx & 127;
        size_t o = (size_t)(b0 + r) * HDIM + h;
        float v = qhp[o];
        #pragma unroll
        for (int s = 1; s < KSLICES; ++s)
            v += qhp[(size_t)s * (BROWS * HDIM) + o];
        qs[r][h] = v;
    }
    __syncthreads();

    int w = tid >> 6, lane = tid & 63;
    int r = w;
    bool act = (lane < 50);
    int n0 = act ? (2 * lane) : 98;         // clamp: inactive lanes read valid mem
    f32x2 a0_ = (f32x2)(0.f), a1_ = (f32x2)(0.f);
    f32x2 a2_ = (f32x2)(0.f), a3_ = (f32x2)(0.f);
    #pragma unroll 2
    for (int h = 0; h < 32; ++h) {
        // four independent h-slices -> four independent gelu chains in flight
        f32x2 sA = *reinterpret_cast<const f32x2*>(&shwT[(h)      * NSEG + n0]);
        f32x2 sB = *reinterpret_cast<const f32x2*>(&shwT[(h + 32) * NSEG + n0]);
        f32x2 sC = *reinterpret_cast<const f32x2*>(&shwT[(h + 64) * NSEG + n0]);
        f32x2 sD = *reinterpret_cast<const f32x2*>(&shwT[(h + 96) * NSEG + n0]);
        a0_ = __builtin_elementwise_fma(gelu2(qs[r][h]      + sA), (f32x2)(rw2[h]),      a0_);
        a1_ = __builtin_elementwise_fma(gelu2(qs[r][h + 32] + sB), (f32x2)(rw2[h + 32]), a1_);
        a2_ = __builtin_elementwise_fma(gelu2(qs[r][h + 64] + sC), (f32x2)(rw2[h + 64]), a2_);
        a3_ = __builtin_elementwise_fma(gelu2(qs[r][h + 96] + sD), (f32x2)(rw2[h + 96]), a3_);
    }
    f32x2 acc = (a0_ + a1_) + (a2_ + a3_);
    if (act) {
        float rb2f = rb2[0];
        float rel0 = 1.f / (1.f + expf(-(acc.x + rb2f)));
        float rel1 = 1.f / (1.f + expf(-(acc.y + rb2f)));
        scL[r][n0]     = cA[n0] * rel0;      wiL[r][n0]     = impA[n0] * rel0;
        scL[r][n0 + 1] = cA[n0 + 1] * rel1;  wiL[r][n0 + 1] = impA[n0 + 1] * rel1;
    }
    __syncthreads();

    // top-k: wave w -> row w (register-only butterfly, proven r8 form)
    {
        int rr = w;
        float s1 = scL[rr][lane];
        float w1 = wiL[rr][lane];
        int i2 = lane + 64;
        float s2 = (i2 < NSEG) ? scL[rr][i2] : -1e30f;
        float w2 = (i2 < NSEG) ? wiL[rr][i2] : 0.f;

        float wv[TOPK]; int idxv[TOPK]; float wsum = 0.f;
        #pragma unroll
        for (int k = 0; k < TOPK; ++k) {
            float s; int i;
            if (s2 > s1) { s = s2; i = i2; } else { s = s1; i = lane; }
            #pragma unroll
            for (int off = 1; off < 64; off <<= 1) {
                float os = __shfl_xor(s, off);
                int oi = __shfl_xor(i, off);
                if (os > s || (os == s && oi < i)) { s = os; i = oi; }
            }
            float wi = __shfl((i < 64) ? w1 : w2, i & 63);
            idxv[k] = i; wv[k] = wi; wsum += wi;
            if (i == lane) s1 = -1e30f;
            if (i == i2)   s2 = -1e30f;
        }
        // dense W row write: idxv/wv/wsum are uniform across lanes.
        int b = b0 + rr;
        float inv = 1.0f / (wsum + 1e-8f);
        int c0 = 2 * lane, c1 = c0 + 1;      // cols 0..127 covered by 64 lanes
        float w0 = 0.f, w1d = 0.f;
        #pragma unroll
        for (int k = 0; k < TOPK; ++k) {
            float wk = wv[k] * inv;
            if (idxv[k] == c0) w0  = wk;
            if (idxv[k] == c1) w1d = wk;
        }
        uint u0 = __float_as_uint(w0), u1 = __float_as_uint(w1d);
        uint h01 = (u0 >> 16) | (u1 & 0xffff0000u);
        float r0 = w0  - __uint_as_float(u0 & 0xffff0000u);
        float r1 = w1d - __uint_as_float(u1 & 0xffff0000u);
        uint l01 = (__float_as_uint(r0) >> 16) | (__float_as_uint(r1) & 0xffff0000u);
        reinterpret_cast<uint*>(Wh)[b * 64 + lane] = h01;
        reinterpret_cast<uint*>(Wl)[b * 64 + lane] = l01;
    }
}

// ---------- K_wgemm: out = query + W * seg via bf16x3 MFMA ----------
// grid (64, 32), block 256 (4 waves). Block: 64 b-rows x 128 d-cols, K=128
// (4 steps of 32). B from pre-swizzled segI via gl16 double-buffer (k_mid
// clone); A-frags (W rows, already bf16 hi/lo) loaded directly from L2-hot W.
__global__ __launch_bounds__(256)
void k_wgemm(const float* __restrict__ query,
             const ushort* __restrict__ Wh,
             const ushort* __restrict__ Wl,
             const unsigned char* __restrict__ segI,
             float* __restrict__ out) {
    __shared__ __align__(16) ushort Bb[2][8192];   // 32 KB: {hi 8K | lo 8K} per buf
    int tid = threadIdx.x;
    int lane = tid & 63, w = tid >> 6;
    int cl = lane & 15, rg = lane >> 4;
    int wm = w >> 1, wn = w & 1;           // wave quadrant: 32 rows x 64 cols
    int m0 = blockIdx.x * 64;
    int d0 = blockIdx.y * 128;

    const unsigned char* bSrc = segI + (size_t)(blockIdx.y * 4) * 16384 + w * 4096 + lane * 16;

    f32x4 acc[2][4];
    #pragma unroll
    for (int mi = 0; mi < 2; ++mi)
        #pragma unroll
        for (int nf = 0; nf < 4; ++nf) acc[mi][nf] = (f32x4)0.f;

    {   // prologue: stage t=0 into buf 0
        char* bd = (char*)&Bb[0][0] + w * 4096;
        #pragma unroll
        for (int j = 0; j < 4; ++j) gl16(bSrc + j * 1024, bd + j * 1024);
    }
    __syncthreads();

    #pragma unroll
    for (int t = 0; t < 4; ++t) {
        int cur = t & 1;
        if (t < 3) {
            char* bd = (char*)&Bb[cur ^ 1][0] + w * 4096;
            const unsigned char* bs = bSrc + (size_t)(t + 1) * 16384;
            #pragma unroll
            for (int j = 0; j < 4; ++j) gl16(bs + j * 1024, bd + j * 1024);
        }
        bf16x8 ah[2], al[2];
        #pragma unroll
        for (int mi = 0; mi < 2; ++mi) {
            int row = m0 + wm * 32 + mi * 16 + cl;
            size_t ao = (size_t)row * HDIM + t * 32 + rg * 8;
            ah[mi] = *reinterpret_cast<const bf16x8*>(Wh + ao);
            al[mi] = *reinterpret_cast<const bf16x8*>(Wl + ao);
        }
        #pragma unroll
        for (int nf = 0; nf < 4; ++nf) {
            int col = wn * 64 + nf * 16 + cl;
            int Z = (col * 64 + rg * 16) ^ ((col & 7) << 4);
            bf16x8 bh = *reinterpret_cast<const bf16x8*>((const char*)&Bb[cur][0] + Z);
            bf16x8 bl = *reinterpret_cast<const bf16x8*>((const char*)&Bb[cur][0] + 8192 + Z);
            #pragma unroll
            for (int mi = 0; mi < 2; ++mi) {
                acc[mi][nf] = __builtin_amdgcn_mfma_f32_16x16x32_bf16(ah[mi], bh, acc[mi][nf], 0, 0, 0);
                acc[mi][nf] = __builtin_amdgcn_mfma_f32_16x16x32_bf16(al[mi], bh, acc[mi][nf], 0, 0, 0);
                acc[mi][nf] = __builtin_amdgcn_mfma_f32_16x16x32_bf16(ah[mi], bl, acc[mi][nf], 0, 0, 0);
            }
        }
        __syncthreads();
    }

    // epilogue: out = query + acc (C/D layout per measured m89 mapping)
    #pragma unroll
    for (int mi = 0; mi < 2; ++mi) {
        int rowb = m0 + wm * 32 + mi * 16 + rg * 4;
        #pragma unroll
        for (int nf = 0; nf < 4; ++nf) {
            int col = d0 + wn * 64 + nf * 16 + cl;
            #pragma unroll
            for (int r = 0; r < 4; ++r) {
                size_t o = (size_t)(rowb + r) * DDIM + col;
                float v = query[o] + acc[mi][nf][r];
                __builtin_nontemporal_store(v, out + o);
            }
        }
    }
}

extern "C" void kernel_launch(void* const* d_in, const int* in_sizes, int n_in,
                              void* d_out, int out_size, void* d_ws, size_t ws_size,
                              hipStream_t stream) {
    const float* query = (const float*)d_in[0];
    const float* seg   = (const float*)d_in[1];
    const int*   pos   = (const int*)d_in[2];
    const float* iw1   = (const float*)d_in[3];
    const float* ib1   = (const float*)d_in[4];
    const float* iw2   = (const float*)d_in[5];
    const float* ib2   = (const float*)d_in[6];
    const float* rw1   = (const float*)d_in[7];
    const float* rb1   = (const float*)d_in[8];
    const float* rw2   = (const float*)d_in[9];
    const float* rb2   = (const float*)d_in[10];
    float* out = (float*)d_out;

    char* ws = (char*)d_ws;
    float* qhp  = (float*)(ws);                                   // 16 MiB
    float* segp = (float*)(ws + 16 * 1024 * 1024);                // 6.55 MiB
    unsigned char* btI  = (unsigned char*)(ws + 23 * 1024 * 1024); // 2 MiB
    unsigned char* segI = (unsigned char*)(ws + 25 * 1024 * 1024); // 2 MiB
    float* shwT = (float*)(ws + 27 * 1024 * 1024);                // 51.2 KB
    float* impA = (float*)(ws + 27 * 1024 * 1024 + 64 * 1024);
    float* cA   = (float*)(ws + 27 * 1024 * 1024 + 64 * 1024 + 4096);
    ushort* Wh  = (ushort*)(ws + 28 * 1024 * 1024);               // 1 MiB
    ushort* Wl  = (ushort*)(ws + 29 * 1024 * 1024);               // 1 MiB

    hipLaunchKernelGGL(k_front, dim3(1856), dim3(256), 0, stream,
                       seg, iw1, rw1, segp, btI, segI);
    hipLaunchKernelGGL(k_mid, dim3(612), dim3(256), 0, stream,
                       query, btI, qhp, segp, pos, ib1, iw2, ib2, rb1,
                       shwT, impA, cA);
    hipLaunchKernelGGL(k_rel, dim3(BROWS / 4), dim3(256), 0, stream,
                       qhp, shwT, rw2, rb2, impA, cA, Wh, Wl);
    hipLaunchKernelGGL(k_wgemm, dim3(64, 32), dim3(256), 0, stream,
                       query, Wh, Wl, segI, out);
}

// Round 18
// 117.517 us; speedup vs baseline: 1.0406x; 1.0406x over previous
//
#include <hip/hip_runtime.h>
#include <math.h>

#define DDIM 4096
#define NSEG 100
#define HDIM 128
#define BROWS 4096
#define TOPK 10
#define KSLICES 8

typedef __attribute__((ext_vector_type(8))) short bf16x8;
typedef __attribute__((ext_vector_type(4))) float f32x4;
typedef __attribute__((ext_vector_type(2))) float f32x2;

// async global->LDS, 16 B per lane; dest = uniform base + lane*16 (HW rule).
__device__ __forceinline__ void gl16(const void* g, void* l) {
    __builtin_amdgcn_global_load_lds(
        (const __attribute__((address_space(1))) unsigned int*)g,
        (__attribute__((address_space(3))) unsigned int*)l,
        16, 0, 0);
}

// Branch-free gelu: A&S 7.1.26 erf (abs err <= 1.5e-7), v_exp_f32 + v_rcp_f32.
__device__ __forceinline__ float gelu_f(float x) {
    float u  = x * 0.70710678118654752440f;
    float au = fminf(fabsf(u), 3.9f);                 // erf(3.9) == 1 to fp32
    float t  = __builtin_amdgcn_rcpf(fmaf(0.3275911f, au, 1.0f));
    float p  = fmaf(fmaf(fmaf(fmaf(1.061405429f, t, -1.453152027f), t,
                              1.421413741f), t, -0.284496736f), t, 0.254829592f) * t;
    float e  = __expf(-au * au);
    float er = fmaf(-p, e, 1.0f);                     // erf(|u|)
    er = copysignf(er, u);
    return 0.5f * x * (1.0f + er);
}

// Packed-pair gelu: identical math per component (VOP3P v_pk_* IEEE == scalar).
__device__ __forceinline__ f32x2 gelu2(f32x2 x) {
    f32x2 u  = x * 0.70710678118654752440f;
    f32x2 au = __builtin_elementwise_min(__builtin_elementwise_abs(u), (f32x2)(3.9f));
    f32x2 den = __builtin_elementwise_fma((f32x2)(0.3275911f), au, (f32x2)(1.0f));
    f32x2 t;
    t.x = __builtin_amdgcn_rcpf(den.x);
    t.y = __builtin_amdgcn_rcpf(den.y);
    f32x2 p = __builtin_elementwise_fma(
                __builtin_elementwise_fma(
                  __builtin_elementwise_fma(
                    __builtin_elementwise_fma((f32x2)(1.061405429f), t, (f32x2)(-1.453152027f)),
                    t, (f32x2)(1.421413741f)),
                  t, (f32x2)(-0.284496736f)),
                t, (f32x2)(0.254829592f)) * t;
    f32x2 e;
    e.x = __expf(-au.x * au.x);
    e.y = __expf(-au.y * au.y);
    f32x2 er = __builtin_elementwise_fma(-p, e, (f32x2)(1.0f));
    er.x = copysignf(er.x, u.x);
    er.y = copysignf(er.y, u.y);
    return 0.5f * x * ((f32x2)(1.0f) + er);
}

// Split fp32 -> bf16 hi (truncate) + bf16 lo (exact residual, truncated).
__device__ __forceinline__ void split8(const float4& a, const float4& b,
                                       bf16x8& hi, bf16x8& lo) {
    float v[8] = {a.x, a.y, a.z, a.w, b.x, b.y, b.z, b.w};
    uint hw[4], lw[4];
    #pragma unroll
    for (int j = 0; j < 4; ++j) {
        uint u0 = __float_as_uint(v[2 * j]);
        uint u1 = __float_as_uint(v[2 * j + 1]);
        hw[j] = (u0 >> 16) | (u1 & 0xffff0000u);
        float r0 = v[2 * j]     - __uint_as_float(u0 & 0xffff0000u);
        float r1 = v[2 * j + 1] - __uint_as_float(u1 & 0xffff0000u);
        lw[j] = (__float_as_uint(r0) >> 16) | (__float_as_uint(r1) & 0xffff0000u);
    }
    uint4 h = make_uint4(hw[0], hw[1], hw[2], hw[3]);
    uint4 l = make_uint4(lw[0], lw[1], lw[2], lw[3]);
    hi = __builtin_bit_cast(bf16x8, h);
    lo = __builtin_bit_cast(bf16x8, l);
}

// ---------- K_front: seg_gemm (blocks 0..1599) || bt (blocks 1600..1727) ----------
__global__ void k_front(const float* __restrict__ seg,
                        const float* __restrict__ iw1,
                        const float* __restrict__ rw1,
                        float* __restrict__ segp,
                        unsigned char* __restrict__ btI) {
    __shared__ __align__(16) float shf[32 * 129];   // 16.5 KB, union for both parts
    int bid = blockIdx.x, tid = threadIdx.x;
    if (bid < 1600) {
        float (*segT)[5] = reinterpret_cast<float (*)[5]>(shf);
        int ng = bid % 25;
        int ks = (bid / 25) * 64;
        {
            int k = tid & 63, j = tid >> 6;
            segT[k][j] = seg[(size_t)(ng * 4 + j) * DDIM + ks + k];
        }
        __syncthreads();
        int col = tid;
        float a0 = 0.f, a1 = 0.f, a2 = 0.f, a3 = 0.f;
        const float* w = (col < HDIM) ? (iw1 + col)
                                      : (rw1 + (size_t)DDIM * HDIM + (col - HDIM));
        #pragma unroll 8
        for (int k = 0; k < 64; ++k) {
            float wv = w[(size_t)(ks + k) * HDIM];
            a0 = fmaf(segT[k][0], wv, a0);
            a1 = fmaf(segT[k][1], wv, a1);
            a2 = fmaf(segT[k][2], wv, a2);
            a3 = fmaf(segT[k][3], wv, a3);
        }
        float* outp = segp + (size_t)(bid / 25) * (NSEG * 256) + (size_t)(ng * 4) * 256 + col;
        outp[0] = a0; outp[256] = a1; outp[512] = a2; outp[768] = a3;
    } else {
        float (*tile)[129] = reinterpret_cast<float (*)[129]>(shf);
        int c = bid - 1600;
        #pragma unroll
        for (int i = 0; i < 4; ++i) {
            int e = i * 1024 + tid * 4;
            int k = e >> 7, n = e & 127;
            *reinterpret_cast<float4*>(&tile[k][n]) =
                *reinterpret_cast<const float4*>(rw1 + (size_t)(c * 32 + k) * HDIM + n);
        }
        __syncthreads();
        unsigned char* img = btI + (size_t)c * 16384;
        #pragma unroll
        for (int uu = 0; uu < 2; ++uu) {
            int U = tid * 2 + uu;            // 0..511
            int col = U >> 2;
            int u = U & 3;
            int Z = (col * 64 + u * 16) ^ ((col & 7) << 4);
            uint hw[4], lw[4];
            #pragma unroll
            for (int j = 0; j < 4; ++j) {
                float x0 = tile[u * 8 + 2 * j][col];
                float x1 = tile[u * 8 + 2 * j + 1][col];
                uint u0 = __float_as_uint(x0), u1 = __float_as_uint(x1);
                hw[j] = (u0 >> 16) | (u1 & 0xffff0000u);
                float r0 = x0 - __uint_as_float(u0 & 0xffff0000u);
                float r1 = x1 - __uint_as_float(u1 & 0xffff0000u);
                lw[j] = (__float_as_uint(r0) >> 16) | (__float_as_uint(r1) & 0xffff0000u);
            }
            *reinterpret_cast<uint4*>(img + Z)        = make_uint4(hw[0], hw[1], hw[2], hw[3]);
            *reinterpret_cast<uint4*>(img + 8192 + Z) = make_uint4(lw[0], lw[1], lw[2], lw[3]);
        }
    }
}

// ---------- K_mid: qh_mfma (blocks 0..511) || seg_red (blocks 512..611) ----------
__global__ __launch_bounds__(256)
void k_mid(const float* __restrict__ query,
           const unsigned char* __restrict__ btI,
           float* __restrict__ qhp,
           const float* __restrict__ segp,
           const int* __restrict__ positions,
           const float* __restrict__ ib1,
           const float* __restrict__ iw2,
           const float* __restrict__ ib2,
           const float* __restrict__ rb1,
           float* __restrict__ shwT, float* __restrict__ impA,
           float* __restrict__ cA) {
    __shared__ __align__(16) char lds[49152];       // qh: Ab 16K | Bb 32K; seg_red: red 512B
    int bid = blockIdx.x, tid = threadIdx.x;
    if (bid < 512) {
        float  (*Ab)[2048] = reinterpret_cast<float (*)[2048]>(lds);
        ushort (*Bb)[8192] = reinterpret_cast<ushort (*)[8192]>(lds + 16384);
        int lane = tid & 63, w = tid >> 6;
        int cl = lane & 15, rg = lane >> 4;
        int wm = w >> 1, wn = w & 1;       // wave quadrant: 32 rows x 64 cols
        int m0 = (bid & 63) * 64;
        int ky = bid >> 6;
        int k0 = ky * 512;

        const float* aSrc0;
        const float* aSrc1;
        {
            int X0 = w * 2048 + lane * 16;
            int r0_ = X0 >> 7, kb0 = (X0 & 127) ^ ((r0_ & 7) << 4);
            aSrc0 = query + (size_t)(m0 + r0_) * DDIM + k0 + (kb0 >> 2);
            int X1 = X0 + 1024;
            int r1_ = X1 >> 7, kb1 = (X1 & 127) ^ ((r1_ & 7) << 4);
            aSrc1 = query + (size_t)(m0 + r1_) * DDIM + k0 + (kb1 >> 2);
        }
        const unsigned char* bSrc = btI + (size_t)(ky * 16) * 16384 + w * 4096 + lane * 16;

        f32x4 acc[2][4];
        #pragma unroll
        for (int mi = 0; mi < 2; ++mi)
            #pragma unroll
            for (int nf = 0; nf < 4; ++nf) acc[mi][nf] = (f32x4)0.f;

        {
            char* ad = (char*)&Ab[0][0] + w * 2048;
            char* bd = (char*)&Bb[0][0] + w * 4096;
            gl16(aSrc0, ad);
            gl16(aSrc1, ad + 1024);
            #pragma unroll
            for (int j = 0; j < 4; ++j) gl16(bSrc + j * 1024, bd + j * 1024);
        }
        __syncthreads();

        #pragma unroll 2
        for (int t = 0; t < 16; ++t) {
            int cur = t & 1;
            if (t < 15) {
                char* ad = (char*)&Ab[cur ^ 1][0] + w * 2048;
                char* bd = (char*)&Bb[cur ^ 1][0] + w * 4096;
                gl16(aSrc0 + (t + 1) * 32, ad);
                gl16(aSrc1 + (t + 1) * 32, ad + 1024);
                const unsigned char* bs = bSrc + (size_t)(t + 1) * 16384;
                #pragma unroll
                for (int j = 0; j < 4; ++j) gl16(bs + j * 1024, bd + j * 1024);
            }
            bf16x8 ah[2], al[2];
            #pragma unroll
            for (int mi = 0; mi < 2; ++mi) {
                int row = wm * 32 + mi * 16 + cl;
                int sw = (row & 7) << 4;
                int Sb = row * 128 + rg * 32;
                float4 f0 = *reinterpret_cast<const float4*>((const char*)&Ab[cur][0] + (Sb ^ sw));
                float4 f1 = *reinterpret_cast<const float4*>((const char*)&Ab[cur][0] + ((Sb + 16) ^ sw));
                split8(f0, f1, ah[mi], al[mi]);
            }
            #pragma unroll
            for (int nf = 0; nf < 4; ++nf) {
                int col = wn * 64 + nf * 16 + cl;
                int Z = (col * 64 + rg * 16) ^ ((col & 7) << 4);
                // buffer layout: {hi 0..8191 | lo 8192..16383} BYTES within Bb[cur]
                bf16x8 bh = *reinterpret_cast<const bf16x8*>((const char*)&Bb[cur][0] + Z);
                bf16x8 bl = *reinterpret_cast<const bf16x8*>((const char*)&Bb[cur][0] + 8192 + Z);
                #pragma unroll
                for (int mi = 0; mi < 2; ++mi) {
                    acc[mi][nf] = __builtin_amdgcn_mfma_f32_16x16x32_bf16(ah[mi], bh, acc[mi][nf], 0, 0, 0);
                    acc[mi][nf] = __builtin_amdgcn_mfma_f32_16x16x32_bf16(al[mi], bh, acc[mi][nf], 0, 0, 0);
                    acc[mi][nf] = __builtin_amdgcn_mfma_f32_16x16x32_bf16(ah[mi], bl, acc[mi][nf], 0, 0, 0);
                }
            }
            __syncthreads();
        }

        float* op = qhp + (size_t)ky * (BROWS * HDIM);
        #pragma unroll
        for (int mi = 0; mi < 2; ++mi) {
            int rowb = m0 + wm * 32 + mi * 16 + rg * 4;
            #pragma unroll
            for (int nf = 0; nf < 4; ++nf) {
                int col = wn * 64 + nf * 16 + cl;
                #pragma unroll
                for (int r = 0; r < 4; ++r)
                    op[(size_t)(rowb + r) * HDIM + col] = acc[mi][nf][r];
            }
        }
    } else {
        float* red = reinterpret_cast<float*>(lds);
        int n = bid - 512;
        float v = 0.f;
        #pragma unroll
        for (int s = 0; s < 64; ++s)
            v += segp[(size_t)s * (NSEG * 256) + (size_t)n * 256 + tid];
        if (tid < HDIM) {
            red[tid] = gelu_f(v + ib1[tid]) * iw2[tid];
        } else {
            shwT[(size_t)(tid - HDIM) * NSEG + n] = v + rb1[tid - HDIM];
        }
        __syncthreads();
        if (tid == 0) {
            float s = 0.f;
            for (int j = 0; j < HDIM; ++j) s += red[j];
            float imp = 1.f / (1.f + expf(-(s + ib2[0])));
            float pf = powf(0.95f, (float)NSEG - (float)positions[n] - 1.0f);
            impA[n] = imp;
            cA[n] = imp * (0.5f + 0.5f * pf);
        }
    }
}

// ---------- K4a: rel scores + top-10 -> idxA/wnA (r16-proven) ----------
// grid 1024, block 256 (4 waves): wave w owns row b0+w; lane l owns segments
// {2l, 2l+1}. Packed f32x2 gelu + 4 independent h-slice chains.
__global__ __launch_bounds__(256)
void k_rel(const float* __restrict__ qhp,
           const float* __restrict__ shwT,
           const float* __restrict__ rw2,
           const float* __restrict__ rb2,
           const float* __restrict__ impA,
           const float* __restrict__ cA,
           int* __restrict__ idxA,
           float* __restrict__ wnA) {
    __shared__ float qs[4][HDIM];
    __shared__ float scL[4][128], wiL[4][128];
    int tid = threadIdx.x;
    int b0 = blockIdx.x * 4;

    // stage qs: 4 rows x 128 h = 512 sums; thread stages idx = tid, tid+256
    #pragma unroll
    for (int i = 0; i < 2; ++i) {
        int idx = tid + i * 256;
        int r = idx >> 7, h = idx & 127;
        size_t o = (size_t)(b0 + r) * HDIM + h;
        float v = qhp[o];
        #pragma unroll
        for (int s = 1; s < KSLICES; ++s)
            v += qhp[(size_t)s * (BROWS * HDIM) + o];
        qs[r][h] = v;
    }
    __syncthreads();

    int w = tid >> 6, lane = tid & 63;
    int r = w;
    bool act = (lane < 50);
    int n0 = act ? (2 * lane) : 98;         // clamp: inactive lanes read valid mem
    f32x2 a0_ = (f32x2)(0.f), a1_ = (f32x2)(0.f);
    f32x2 a2_ = (f32x2)(0.f), a3_ = (f32x2)(0.f);
    #pragma unroll 2
    for (int h = 0; h < 32; ++h) {
        // four independent h-slices -> four independent gelu chains in flight
        f32x2 sA = *reinterpret_cast<const f32x2*>(&shwT[(h)      * NSEG + n0]);
        f32x2 sB = *reinterpret_cast<const f32x2*>(&shwT[(h + 32) * NSEG + n0]);
        f32x2 sC = *reinterpret_cast<const f32x2*>(&shwT[(h + 64) * NSEG + n0]);
        f32x2 sD = *reinterpret_cast<const f32x2*>(&shwT[(h + 96) * NSEG + n0]);
        a0_ = __builtin_elementwise_fma(gelu2(qs[r][h]      + sA), (f32x2)(rw2[h]),      a0_);
        a1_ = __builtin_elementwise_fma(gelu2(qs[r][h + 32] + sB), (f32x2)(rw2[h + 32]), a1_);
        a2_ = __builtin_elementwise_fma(gelu2(qs[r][h + 64] + sC), (f32x2)(rw2[h + 64]), a2_);
        a3_ = __builtin_elementwise_fma(gelu2(qs[r][h + 96] + sD), (f32x2)(rw2[h + 96]), a3_);
    }
    f32x2 acc = (a0_ + a1_) + (a2_ + a3_);
    if (act) {
        float rb2f = rb2[0];
        float rel0 = 1.f / (1.f + expf(-(acc.x + rb2f)));
        float rel1 = 1.f / (1.f + expf(-(acc.y + rb2f)));
        scL[r][n0]     = cA[n0] * rel0;      wiL[r][n0]     = impA[n0] * rel0;
        scL[r][n0 + 1] = cA[n0 + 1] * rel1;  wiL[r][n0 + 1] = impA[n0 + 1] * rel1;
    }
    __syncthreads();

    // top-k: wave w -> row w (register-only butterfly, proven r8 form)
    {
        int rr = w;
        float s1 = scL[rr][lane];
        float w1 = wiL[rr][lane];
        int i2 = lane + 64;
        float s2 = (i2 < NSEG) ? scL[rr][i2] : -1e30f;
        float w2 = (i2 < NSEG) ? wiL[rr][i2] : 0.f;

        float wv[TOPK]; int idxv[TOPK]; float wsum = 0.f;
        #pragma unroll
        for (int k = 0; k < TOPK; ++k) {
            float s; int i;
            if (s2 > s1) { s = s2; i = i2; } else { s = s1; i = lane; }
            #pragma unroll
            for (int off = 1; off < 64; off <<= 1) {
                float os = __shfl_xor(s, off);
                int oi = __shfl_xor(i, off);
                if (os > s || (os == s && oi < i)) { s = os; i = oi; }
            }
            float wi = __shfl((i < 64) ? w1 : w2, i & 63);
            idxv[k] = i; wv[k] = wi; wsum += wi;
            if (i == lane) s1 = -1e30f;
            if (i == i2)   s2 = -1e30f;
        }
        if (lane == 0) {
            int b = b0 + rr;
            float denom = wsum + 1e-8f;
            #pragma unroll
            for (int k = 0; k < TOPK; ++k) {
                idxA[b * TOPK + k] = idxv[k];
                wnA[b * TOPK + k]  = wv[k] / denom;
            }
        }
    }
}

// ---------- K4c: gather with gl16-staged seg rows (r7 lesson applied) ----------
// grid 4096, block 256 (4 waves). Per chunk c (512 floats of the d-range):
// 20 async gl16 stage the 10 selected rows' 2KB slices into LDS (double-buffered,
// 2x20KB); loads issue back-to-back (no dest reg -> compiler can't sink them),
// drain once at the barrier. Compute: 10 float2 LDS reads + FMA in k-order
// (bit-identical math to the flat version), nt-store.
__global__ __launch_bounds__(256)
void k_gather(const float* __restrict__ query,
              const float* __restrict__ seg,
              const int* __restrict__ idxA,
              const float* __restrict__ wnA,
              float* __restrict__ out) {
    __shared__ __align__(16) float sbuf[2][20 * 256];   // 2 x 20 KB
    int b = blockIdx.x, tid = threadIdx.x;
    int lane = tid & 63, w = tid >> 6;
    const int*   ip = idxA + b * TOPK;
    const float* wp = wnA  + b * TOPK;
    float wn[TOPK]; const float* srow[TOPK];
    #pragma unroll
    for (int k = 0; k < TOPK; ++k) {
        wn[k]   = wp[k];                          // uniform -> s_load
        srow[k] = seg + (size_t)ip[k] * DDIM;     // uniform -> sgpr base
    }
    const float* qrow = query + (size_t)b * DDIM;
    float* orow = out + (size_t)b * DDIM;

    // stage chunk c into buffer buf: sub-chunk m = w*5+j covers row k=m>>1,
    // half=(m&1); 256 floats each; src per-lane +lane*4 floats (HW adds lane*16B
    // to the LDS dest).
    #define STAGE(c, buf)                                                        \
        _Pragma("unroll")                                                        \
        for (int j = 0; j < 5; ++j) {                                            \
            int m = w * 5 + j;                                                   \
            gl16(srow[m >> 1] + (c) * 512 + (m & 1) * 256 + lane * 4,            \
                 (char*)&sbuf[buf][0] + m * 1024);                               \
        }

    STAGE(0, 0)
    __syncthreads();

    #pragma unroll
    for (int c = 0; c < 8; ++c) {
        int buf = c & 1;
        if (c < 7) { STAGE(c + 1, buf ^ 1) }
        float2 q2 = *reinterpret_cast<const float2*>(qrow + c * 512 + tid * 2);
        const float2* s2 = reinterpret_cast<const float2*>(&sbuf[buf][0]);
        #pragma unroll
        for (int k = 0; k < TOPK; ++k) {
            float2 sv = s2[k * 256 + tid];
            q2.x = fmaf(wn[k], sv.x, q2.x);
            q2.y = fmaf(wn[k], sv.y, q2.y);
        }
        f32x2 v; v.x = q2.x; v.y = q2.y;
        __builtin_nontemporal_store(v, reinterpret_cast<f32x2*>(orow + c * 512 + tid * 2));
        __syncthreads();
    }
    #undef STAGE
}

extern "C" void kernel_launch(void* const* d_in, const int* in_sizes, int n_in,
                              void* d_out, int out_size, void* d_ws, size_t ws_size,
                              hipStream_t stream) {
    const float* query = (const float*)d_in[0];
    const float* seg   = (const float*)d_in[1];
    const int*   pos   = (const int*)d_in[2];
    const float* iw1   = (const float*)d_in[3];
    const float* ib1   = (const float*)d_in[4];
    const float* iw2   = (const float*)d_in[5];
    const float* ib2   = (const float*)d_in[6];
    const float* rw1   = (const float*)d_in[7];
    const float* rb1   = (const float*)d_in[8];
    const float* rw2   = (const float*)d_in[9];
    const float* rb2   = (const float*)d_in[10];
    float* out = (float*)d_out;

    char* ws = (char*)d_ws;
    // qhp written by k_mid's qh blocks while seg_red blocks read segp -> keep
    // them in SEPARATE regions (they are live in the same launch).
    float* qhp  = (float*)(ws);                                   // 16 MiB
    float* segp = (float*)(ws + 16 * 1024 * 1024);                // 6.55 MiB
    unsigned char* btI = (unsigned char*)(ws + 23 * 1024 * 1024); // 2 MiB
    float* shwT = (float*)(ws + 25 * 1024 * 1024);                // 51.2 KB
    float* impA = (float*)(ws + 25 * 1024 * 1024 + 64 * 1024);
    float* cA   = (float*)(ws + 25 * 1024 * 1024 + 64 * 1024 + 4096);
    int*   idxA = (int*)  (ws + 25 * 1024 * 1024 + 128 * 1024);   // 160 KB
    float* wnA  = (float*)(ws + 25 * 1024 * 1024 + 320 * 1024);   // 160 KB

    hipLaunchKernelGGL(k_front, dim3(1728), dim3(256), 0, stream,
                       seg, iw1, rw1, segp, btI);
    hipLaunchKernelGGL(k_mid, dim3(612), dim3(256), 0, stream,
                       query, btI, qhp, segp, pos, ib1, iw2, ib2, rb1,
                       shwT, impA, cA);
    hipLaunchKernelGGL(k_rel, dim3(BROWS / 4), dim3(256), 0, stream,
                       qhp, shwT, rw2, rb2, impA, cA, idxA, wnA);
    hipLaunchKernelGGL(k_gather, dim3(BROWS), dim3(256), 0, stream,
                       query, seg, idxA, wnA, out);
}

// Round 19
// 111.118 us; speedup vs baseline: 1.1005x; 1.0576x over previous
//
#include <hip/hip_runtime.h>
#include <math.h>

#define DDIM 4096
#define NSEG 100
#define HDIM 128
#define BROWS 4096
#define TOPK 10
#define KSLICES 8

typedef __attribute__((ext_vector_type(8))) short bf16x8;
typedef __attribute__((ext_vector_type(4))) float f32x4;
typedef __attribute__((ext_vector_type(2))) float f32x2;

// async global->LDS, 16 B per lane; dest = uniform base + lane*16 (HW rule).
__device__ __forceinline__ void gl16(const void* g, void* l) {
    __builtin_amdgcn_global_load_lds(
        (const __attribute__((address_space(1))) unsigned int*)g,
        (__attribute__((address_space(3))) unsigned int*)l,
        16, 0, 0);
}

// Branch-free gelu: A&S 7.1.26 erf (abs err <= 1.5e-7), v_exp_f32 + v_rcp_f32.
__device__ __forceinline__ float gelu_f(float x) {
    float u  = x * 0.70710678118654752440f;
    float au = fminf(fabsf(u), 3.9f);                 // erf(3.9) == 1 to fp32
    float t  = __builtin_amdgcn_rcpf(fmaf(0.3275911f, au, 1.0f));
    float p  = fmaf(fmaf(fmaf(fmaf(1.061405429f, t, -1.453152027f), t,
                              1.421413741f), t, -0.284496736f), t, 0.254829592f) * t;
    float e  = __expf(-au * au);
    float er = fmaf(-p, e, 1.0f);                     // erf(|u|)
    er = copysignf(er, u);
    return 0.5f * x * (1.0f + er);
}

// Packed-pair gelu: identical math per component (VOP3P v_pk_* IEEE == scalar).
__device__ __forceinline__ f32x2 gelu2(f32x2 x) {
    f32x2 u  = x * 0.70710678118654752440f;
    f32x2 au = __builtin_elementwise_min(__builtin_elementwise_abs(u), (f32x2)(3.9f));
    f32x2 den = __builtin_elementwise_fma((f32x2)(0.3275911f), au, (f32x2)(1.0f));
    f32x2 t;
    t.x = __builtin_amdgcn_rcpf(den.x);
    t.y = __builtin_amdgcn_rcpf(den.y);
    f32x2 p = __builtin_elementwise_fma(
                __builtin_elementwise_fma(
                  __builtin_elementwise_fma(
                    __builtin_elementwise_fma((f32x2)(1.061405429f), t, (f32x2)(-1.453152027f)),
                    t, (f32x2)(1.421413741f)),
                  t, (f32x2)(-0.284496736f)),
                t, (f32x2)(0.254829592f)) * t;
    f32x2 e;
    e.x = __expf(-au.x * au.x);
    e.y = __expf(-au.y * au.y);
    f32x2 er = __builtin_elementwise_fma(-p, e, (f32x2)(1.0f));
    er.x = copysignf(er.x, u.x);
    er.y = copysignf(er.y, u.y);
    return 0.5f * x * ((f32x2)(1.0f) + er);
}

// Split fp32 -> bf16 hi (truncate) + bf16 lo (exact residual, truncated).
__device__ __forceinline__ void split8(const float4& a, const float4& b,
                                       bf16x8& hi, bf16x8& lo) {
    float v[8] = {a.x, a.y, a.z, a.w, b.x, b.y, b.z, b.w};
    uint hw[4], lw[4];
    #pragma unroll
    for (int j = 0; j < 4; ++j) {
        uint u0 = __float_as_uint(v[2 * j]);
        uint u1 = __float_as_uint(v[2 * j + 1]);
        hw[j] = (u0 >> 16) | (u1 & 0xffff0000u);
        float r0 = v[2 * j]     - __uint_as_float(u0 & 0xffff0000u);
        float r1 = v[2 * j + 1] - __uint_as_float(u1 & 0xffff0000u);
        lw[j] = (__float_as_uint(r0) >> 16) | (__float_as_uint(r1) & 0xffff0000u);
    }
    uint4 h = make_uint4(hw[0], hw[1], hw[2], hw[3]);
    uint4 l = make_uint4(lw[0], lw[1], lw[2], lw[3]);
    hi = __builtin_bit_cast(bf16x8, h);
    lo = __builtin_bit_cast(bf16x8, l);
}

// ---------- K_front: seg_gemm (blocks 0..1599) || bt (blocks 1600..1727) ----------
__global__ void k_front(const float* __restrict__ seg,
                        const float* __restrict__ iw1,
                        const float* __restrict__ rw1,
                        float* __restrict__ segp,
                        unsigned char* __restrict__ btI) {
    __shared__ __align__(16) float shf[32 * 129];   // 16.5 KB, union for both parts
    int bid = blockIdx.x, tid = threadIdx.x;
    if (bid < 1600) {
        float (*segT)[5] = reinterpret_cast<float (*)[5]>(shf);
        int ng = bid % 25;
        int ks = (bid / 25) * 64;
        {
            int k = tid & 63, j = tid >> 6;
            segT[k][j] = seg[(size_t)(ng * 4 + j) * DDIM + ks + k];
        }
        __syncthreads();
        int col = tid;
        float a0 = 0.f, a1 = 0.f, a2 = 0.f, a3 = 0.f;
        const float* w = (col < HDIM) ? (iw1 + col)
                                      : (rw1 + (size_t)DDIM * HDIM + (col - HDIM));
        #pragma unroll 8
        for (int k = 0; k < 64; ++k) {
            float wv = w[(size_t)(ks + k) * HDIM];
            a0 = fmaf(segT[k][0], wv, a0);
            a1 = fmaf(segT[k][1], wv, a1);
            a2 = fmaf(segT[k][2], wv, a2);
            a3 = fmaf(segT[k][3], wv, a3);
        }
        float* outp = segp + (size_t)(bid / 25) * (NSEG * 256) + (size_t)(ng * 4) * 256 + col;
        outp[0] = a0; outp[256] = a1; outp[512] = a2; outp[768] = a3;
    } else {
        float (*tile)[129] = reinterpret_cast<float (*)[129]>(shf);
        int c = bid - 1600;
        #pragma unroll
        for (int i = 0; i < 4; ++i) {
            int e = i * 1024 + tid * 4;
            int k = e >> 7, n = e & 127;
            *reinterpret_cast<float4*>(&tile[k][n]) =
                *reinterpret_cast<const float4*>(rw1 + (size_t)(c * 32 + k) * HDIM + n);
        }
        __syncthreads();
        unsigned char* img = btI + (size_t)c * 16384;
        #pragma unroll
        for (int uu = 0; uu < 2; ++uu) {
            int U = tid * 2 + uu;            // 0..511
            int col = U >> 2;
            int u = U & 3;
            int Z = (col * 64 + u * 16) ^ ((col & 7) << 4);
            uint hw[4], lw[4];
            #pragma unroll
            for (int j = 0; j < 4; ++j) {
                float x0 = tile[u * 8 + 2 * j][col];
                float x1 = tile[u * 8 + 2 * j + 1][col];
                uint u0 = __float_as_uint(x0), u1 = __float_as_uint(x1);
                hw[j] = (u0 >> 16) | (u1 & 0xffff0000u);
                float r0 = x0 - __uint_as_float(u0 & 0xffff0000u);
                float r1 = x1 - __uint_as_float(u1 & 0xffff0000u);
                lw[j] = (__float_as_uint(r0) >> 16) | (__float_as_uint(r1) & 0xffff0000u);
            }
            *reinterpret_cast<uint4*>(img + Z)        = make_uint4(hw[0], hw[1], hw[2], hw[3]);
            *reinterpret_cast<uint4*>(img + 8192 + Z) = make_uint4(lw[0], lw[1], lw[2], lw[3]);
        }
    }
}

// ---------- K_mid: qh_mfma (blocks 0..511) || seg_red (blocks 512..611) ----------
__global__ __launch_bounds__(256)
void k_mid(const float* __restrict__ query,
           const unsigned char* __restrict__ btI,
           float* __restrict__ qhp,
           const float* __restrict__ segp,
           const int* __restrict__ positions,
           const float* __restrict__ ib1,
           const float* __restrict__ iw2,
           const float* __restrict__ ib2,
           const float* __restrict__ rb1,
           float* __restrict__ shwT, float* __restrict__ impA,
           float* __restrict__ cA) {
    __shared__ __align__(16) char lds[49152];       // qh: Ab 16K | Bb 32K; seg_red: red 512B
    int bid = blockIdx.x, tid = threadIdx.x;
    if (bid < 512) {
        float  (*Ab)[2048] = reinterpret_cast<float (*)[2048]>(lds);
        ushort (*Bb)[8192] = reinterpret_cast<ushort (*)[8192]>(lds + 16384);
        int lane = tid & 63, w = tid >> 6;
        int cl = lane & 15, rg = lane >> 4;
        int wm = w >> 1, wn = w & 1;       // wave quadrant: 32 rows x 64 cols
        int m0 = (bid & 63) * 64;
        int ky = bid >> 6;
        int k0 = ky * 512;

        const float* aSrc0;
        const float* aSrc1;
        {
            int X0 = w * 2048 + lane * 16;
            int r0_ = X0 >> 7, kb0 = (X0 & 127) ^ ((r0_ & 7) << 4);
            aSrc0 = query + (size_t)(m0 + r0_) * DDIM + k0 + (kb0 >> 2);
            int X1 = X0 + 1024;
            int r1_ = X1 >> 7, kb1 = (X1 & 127) ^ ((r1_ & 7) << 4);
            aSrc1 = query + (size_t)(m0 + r1_) * DDIM + k0 + (kb1 >> 2);
        }
        const unsigned char* bSrc = btI + (size_t)(ky * 16) * 16384 + w * 4096 + lane * 16;

        f32x4 acc[2][4];
        #pragma unroll
        for (int mi = 0; mi < 2; ++mi)
            #pragma unroll
            for (int nf = 0; nf < 4; ++nf) acc[mi][nf] = (f32x4)0.f;

        {
            char* ad = (char*)&Ab[0][0] + w * 2048;
            char* bd = (char*)&Bb[0][0] + w * 4096;
            gl16(aSrc0, ad);
            gl16(aSrc1, ad + 1024);
            #pragma unroll
            for (int j = 0; j < 4; ++j) gl16(bSrc + j * 1024, bd + j * 1024);
        }
        __syncthreads();

        #pragma unroll 2
        for (int t = 0; t < 16; ++t) {
            int cur = t & 1;
            if (t < 15) {
                char* ad = (char*)&Ab[cur ^ 1][0] + w * 2048;
                char* bd = (char*)&Bb[cur ^ 1][0] + w * 4096;
                gl16(aSrc0 + (t + 1) * 32, ad);
                gl16(aSrc1 + (t + 1) * 32, ad + 1024);
                const unsigned char* bs = bSrc + (size_t)(t + 1) * 16384;
                #pragma unroll
                for (int j = 0; j < 4; ++j) gl16(bs + j * 1024, bd + j * 1024);
            }
            bf16x8 ah[2], al[2];
            #pragma unroll
            for (int mi = 0; mi < 2; ++mi) {
                int row = wm * 32 + mi * 16 + cl;
                int sw = (row & 7) << 4;
                int Sb = row * 128 + rg * 32;
                float4 f0 = *reinterpret_cast<const float4*>((const char*)&Ab[cur][0] + (Sb ^ sw));
                float4 f1 = *reinterpret_cast<const float4*>((const char*)&Ab[cur][0] + ((Sb + 16) ^ sw));
                split8(f0, f1, ah[mi], al[mi]);
            }
            #pragma unroll
            for (int nf = 0; nf < 4; ++nf) {
                int col = wn * 64 + nf * 16 + cl;
                int Z = (col * 64 + rg * 16) ^ ((col & 7) << 4);
                // buffer layout: {hi 0..8191 | lo 8192..16383} BYTES within Bb[cur]
                bf16x8 bh = *reinterpret_cast<const bf16x8*>((const char*)&Bb[cur][0] + Z);
                bf16x8 bl = *reinterpret_cast<const bf16x8*>((const char*)&Bb[cur][0] + 8192 + Z);
                #pragma unroll
                for (int mi = 0; mi < 2; ++mi) {
                    acc[mi][nf] = __builtin_amdgcn_mfma_f32_16x16x32_bf16(ah[mi], bh, acc[mi][nf], 0, 0, 0);
                    acc[mi][nf] = __builtin_amdgcn_mfma_f32_16x16x32_bf16(al[mi], bh, acc[mi][nf], 0, 0, 0);
                    acc[mi][nf] = __builtin_amdgcn_mfma_f32_16x16x32_bf16(ah[mi], bl, acc[mi][nf], 0, 0, 0);
                }
            }
            __syncthreads();
        }

        float* op = qhp + (size_t)ky * (BROWS * HDIM);
        #pragma unroll
        for (int mi = 0; mi < 2; ++mi) {
            int rowb = m0 + wm * 32 + mi * 16 + rg * 4;
            #pragma unroll
            for (int nf = 0; nf < 4; ++nf) {
                int col = wn * 64 + nf * 16 + cl;
                #pragma unroll
                for (int r = 0; r < 4; ++r)
                    op[(size_t)(rowb + r) * HDIM + col] = acc[mi][nf][r];
            }
        }
    } else {
        float* red = reinterpret_cast<float*>(lds);
        int n = bid - 512;
        float v = 0.f;
        #pragma unroll
        for (int s = 0; s < 64; ++s)
            v += segp[(size_t)s * (NSEG * 256) + (size_t)n * 256 + tid];
        if (tid < HDIM) {
            red[tid] = gelu_f(v + ib1[tid]) * iw2[tid];
        } else {
            shwT[(size_t)(tid - HDIM) * NSEG + n] = v + rb1[tid - HDIM];
        }
        __syncthreads();
        if (tid == 0) {
            float s = 0.f;
            for (int j = 0; j < HDIM; ++j) s += red[j];
            float imp = 1.f / (1.f + expf(-(s + ib2[0])));
            float pf = powf(0.95f, (float)NSEG - (float)positions[n] - 1.0f);
            impA[n] = imp;
            cA[n] = imp * (0.5f + 0.5f * pf);
        }
    }
}

// ---------- K4a: rel scores + top-10 -> idxA/wnA (r16-proven best) ----------
// grid 1024, block 256 (4 waves): wave w owns row b0+w; lane l owns segments
// {2l, 2l+1}. Packed f32x2 gelu + 4 independent h-slice chains.
__global__ __launch_bounds__(256)
void k_rel(const float* __restrict__ qhp,
           const float* __restrict__ shwT,
           const float* __restrict__ rw2,
           const float* __restrict__ rb2,
           const float* __restrict__ impA,
           const float* __restrict__ cA,
           int* __restrict__ idxA,
           float* __restrict__ wnA) {
    __shared__ float qs[4][HDIM];
    __shared__ float scL[4][128], wiL[4][128];
    int tid = threadIdx.x;
    int b0 = blockIdx.x * 4;

    // stage qs: 4 rows x 128 h = 512 sums; thread stages idx = tid, tid+256
    #pragma unroll
    for (int i = 0; i < 2; ++i) {
        int idx = tid + i * 256;
        int r = idx >> 7, h = idx & 127;
        size_t o = (size_t)(b0 + r) * HDIM + h;
        float v = qhp[o];
        #pragma unroll
        for (int s = 1; s < KSLICES; ++s)
            v += qhp[(size_t)s * (BROWS * HDIM) + o];
        qs[r][h] = v;
    }
    __syncthreads();

    int w = tid >> 6, lane = tid & 63;
    int r = w;
    bool act = (lane < 50);
    int n0 = act ? (2 * lane) : 98;         // clamp: inactive lanes read valid mem
    f32x2 a0_ = (f32x2)(0.f), a1_ = (f32x2)(0.f);
    f32x2 a2_ = (f32x2)(0.f), a3_ = (f32x2)(0.f);
    #pragma unroll 2
    for (int h = 0; h < 32; ++h) {
        // four independent h-slices -> four independent gelu chains in flight
        f32x2 sA = *reinterpret_cast<const f32x2*>(&shwT[(h)      * NSEG + n0]);
        f32x2 sB = *reinterpret_cast<const f32x2*>(&shwT[(h + 32) * NSEG + n0]);
        f32x2 sC = *reinterpret_cast<const f32x2*>(&shwT[(h + 64) * NSEG + n0]);
        f32x2 sD = *reinterpret_cast<const f32x2*>(&shwT[(h + 96) * NSEG + n0]);
        a0_ = __builtin_elementwise_fma(gelu2(qs[r][h]      + sA), (f32x2)(rw2[h]),      a0_);
        a1_ = __builtin_elementwise_fma(gelu2(qs[r][h + 32] + sB), (f32x2)(rw2[h + 32]), a1_);
        a2_ = __builtin_elementwise_fma(gelu2(qs[r][h + 64] + sC), (f32x2)(rw2[h + 64]), a2_);
        a3_ = __builtin_elementwise_fma(gelu2(qs[r][h + 96] + sD), (f32x2)(rw2[h + 96]), a3_);
    }
    f32x2 acc = (a0_ + a1_) + (a2_ + a3_);
    if (act) {
        float rb2f = rb2[0];
        float rel0 = 1.f / (1.f + expf(-(acc.x + rb2f)));
        float rel1 = 1.f / (1.f + expf(-(acc.y + rb2f)));
        scL[r][n0]     = cA[n0] * rel0;      wiL[r][n0]     = impA[n0] * rel0;
        scL[r][n0 + 1] = cA[n0 + 1] * rel1;  wiL[r][n0 + 1] = impA[n0 + 1] * rel1;
    }
    __syncthreads();

    // top-k: wave w -> row w (register-only butterfly, proven r8 form)
    {
        int rr = w;
        float s1 = scL[rr][lane];
        float w1 = wiL[rr][lane];
        int i2 = lane + 64;
        float s2 = (i2 < NSEG) ? scL[rr][i2] : -1e30f;
        float w2 = (i2 < NSEG) ? wiL[rr][i2] : 0.f;

        float wv[TOPK]; int idxv[TOPK]; float wsum = 0.f;
        #pragma unroll
        for (int k = 0; k < TOPK; ++k) {
            float s; int i;
            if (s2 > s1) { s = s2; i = i2; } else { s = s1; i = lane; }
            #pragma unroll
            for (int off = 1; off < 64; off <<= 1) {
                float os = __shfl_xor(s, off);
                int oi = __shfl_xor(i, off);
                if (os > s || (os == s && oi < i)) { s = os; i = oi; }
            }
            float wi = __shfl((i < 64) ? w1 : w2, i & 63);
            idxv[k] = i; wv[k] = wi; wsum += wi;
            if (i == lane) s1 = -1e30f;
            if (i == i2)   s2 = -1e30f;
        }
        if (lane == 0) {
            int b = b0 + rr;
            float denom = wsum + 1e-8f;
            #pragma unroll
            for (int k = 0; k < TOPK; ++k) {
                idxA[b * TOPK + k] = idxv[k];
                wnA[b * TOPK + k]  = wv[k] / denom;
            }
        }
    }
}

// ---------- K4c: pure streaming gather: out = query + sum wn[k]*seg[idx[k]] ----------
// grid 4096, block 256. Weights/pointers via wave-uniform scalar loads.
// Output stores NONTEMPORAL (out never re-read -> keep L2 hot for seg/query).
__global__ void k_gather(const float* __restrict__ query,
                         const float* __restrict__ seg,
                         const int* __restrict__ idxA,
                         const float* __restrict__ wnA,
                         float* __restrict__ out) {
    int b = blockIdx.x, tid = threadIdx.x;
    const int*   ip = idxA + b * TOPK;
    const float* wp = wnA  + b * TOPK;
    float wn[TOPK]; const float* srow[TOPK];
    #pragma unroll
    for (int k = 0; k < TOPK; ++k) {
        wn[k]   = wp[k];                          // uniform -> s_load
        srow[k] = seg + (size_t)ip[k] * DDIM;     // uniform -> s_load + sgpr addr
    }
    const float* qrow = query + (size_t)b * DDIM;
    float* orow = out + (size_t)b * DDIM;

    float4 q[4];
    #pragma unroll
    for (int c = 0; c < 4; ++c)
        q[c] = *reinterpret_cast<const float4*>(qrow + c * 1024 + tid * 4);
    #pragma unroll
    for (int k = 0; k < TOPK; ++k) {
        float4 s[4];
        #pragma unroll
        for (int c = 0; c < 4; ++c)
            s[c] = *reinterpret_cast<const float4*>(srow[k] + c * 1024 + tid * 4);
        #pragma unroll
        for (int c = 0; c < 4; ++c) {
            q[c].x = fmaf(wn[k], s[c].x, q[c].x);
            q[c].y = fmaf(wn[k], s[c].y, q[c].y);
            q[c].z = fmaf(wn[k], s[c].z, q[c].z);
            q[c].w = fmaf(wn[k], s[c].w, q[c].w);
        }
    }
    #pragma unroll
    for (int c = 0; c < 4; ++c) {
        f32x4 v = __builtin_bit_cast(f32x4, q[c]);
        __builtin_nontemporal_store(v, reinterpret_cast<f32x4*>(orow + c * 1024 + tid * 4));
    }
}

extern "C" void kernel_launch(void* const* d_in, const int* in_sizes, int n_in,
                              void* d_out, int out_size, void* d_ws, size_t ws_size,
                              hipStream_t stream) {
    const float* query = (const float*)d_in[0];
    const float* seg   = (const float*)d_in[1];
    const int*   pos   = (const int*)d_in[2];
    const float* iw1   = (const float*)d_in[3];
    const float* ib1   = (const float*)d_in[4];
    const float* iw2   = (const float*)d_in[5];
    const float* ib2   = (const float*)d_in[6];
    const float* rw1   = (const float*)d_in[7];
    const float* rb1   = (const float*)d_in[8];
    const float* rw2   = (const float*)d_in[9];
    const float* rb2   = (const float*)d_in[10];
    float* out = (float*)d_out;

    char* ws = (char*)d_ws;
    // qhp written by k_mid's qh blocks while seg_red blocks read segp -> keep
    // them in SEPARATE regions (they are live in the same launch).
    float* qhp  = (float*)(ws);                                   // 16 MiB
    float* segp = (float*)(ws + 16 * 1024 * 1024);                // 6.55 MiB
    unsigned char* btI = (unsigned char*)(ws + 23 * 1024 * 1024); // 2 MiB
    float* shwT = (float*)(ws + 25 * 1024 * 1024);                // 51.2 KB
    float* impA = (float*)(ws + 25 * 1024 * 1024 + 64 * 1024);
    float* cA   = (float*)(ws + 25 * 1024 * 1024 + 64 * 1024 + 4096);
    int*   idxA = (int*)  (ws + 25 * 1024 * 1024 + 128 * 1024);   // 160 KB
    float* wnA  = (float*)(ws + 25 * 1024 * 1024 + 320 * 1024);   // 160 KB

    hipLaunchKernelGGL(k_front, dim3(1728), dim3(256), 0, stream,
                       seg, iw1, rw1, segp, btI);
    hipLaunchKernelGGL(k_mid, dim3(612), dim3(256), 0, stream,
                       query, btI, qhp, segp, pos, ib1, iw2, ib2, rb1,
                       shwT, impA, cA);
    hipLaunchKernelGGL(k_rel, dim3(BROWS / 4), dim3(256), 0, stream,
                       qhp, shwT, rw2, rb2, impA, cA, idxA, wnA);
    hipLaunchKernelGGL(k_gather, dim3(BROWS), dim3(256), 0, stream,
                       query, seg, idxA, wnA, out);
}